// Round 7
// baseline (91.212 us; speedup 1.0000x reference)
//
#include <hip/hip_runtime.h>

// NMS-r BP decoder, one block per batch element. Verified structure (round 6):
// 3 rotating LDS colsum buffers, 1 barrier/iteration, 15-CE sort network on
// (v,col) pairs, cv register-resident. This round (latency trims):
//  - buffers are initialized to sp1*soft instead of 0, so the gather is ONE
//    ds_read: v = S[rd][c] - cv  (T = colsum + sp1*soft materialized by the
//    atomics for free). SPS array gone; no p==0 special case.
//  - sign handling via bit ops: sign(P*sg_k) = xor of sign bits; LOO dot is
//    >= 0 (non-negative weights), so cv = or(loo_bits, Pbit ^ sbit_k).
//  - marg columns are (2*tid, 2*tid+1): float2 global I/O, ds b64 accesses
//    (2-way bank aliasing is free).
// Round-4/6 lesson: kernel is latency-bound (VALUBusy ~2%); bench has a
// ~50us fixed harness floor (268MB d_ws poison fill) we don't control.

constexpr int BB    = 64;
constexpr int NCOL  = 1024;
constexpr int KDC   = 6;
constexpr int ITERS = 5;
constexpr int THR   = 512;            // 1 check/thread, 2 marg cols/thread
constexpr int TOT   = BB * NCOL;

__device__ __forceinline__ float softplusf(float x) {
    return fmaxf(x, 0.f) + log1pf(expf(-fabsf(x)));
}

__global__ void __launch_bounds__(THR) k_decode(
        const float* __restrict__ soft,      // [B,N]
        const int*   __restrict__ row_cols,  // [M,DC]
        const float* __restrict__ W1,        // [DC-1,4]
        const float* __restrict__ W2,        // [4]
        const float* __restrict__ bw1,
        const float* __restrict__ bw2,
        float* __restrict__ out) {           // [ITERS+1,B,N]
    __shared__ float S[3][NCOL];   // rotating colsum buffers, base = sp1*soft

    const int tid = threadIdx.x;
    const int b   = blockIdx.x;
    const int n0  = 2 * tid, n1 = 2 * tid + 1;

    const float sp1 = softplusf(bw1[0]);
    const float sp2 = softplusf(bw2[0]);
    const float dsp = sp2 - sp1;

    // collapsed NN: w = W1 @ W2 (5-vector), redundant per-thread (L1-hot)
    float w[KDC - 1];
#pragma unroll
    for (int j = 0; j < KDC - 1; ++j) {
        float a = 0.f;
#pragma unroll
        for (int q = 0; q < 4; ++q) a += W1[j * 4 + q] * W2[q];
        w[j] = a;
    }

    const float2 sv = *reinterpret_cast<const float2*>(soft + b * NCOL + n0);
    const float s0 = sv.x, s1 = sv.y;
    *reinterpret_cast<float2*>(out + b * NCOL + n0) = sv;  // out[0] = input
    const float base0 = sp1 * s0, base1 = sp1 * s1;
    S[0][n0] = base0;  S[0][n1] = base1;   // read at p=0 (T of iter 0)
    S[1][n0] = base0;  S[1][n1] = base1;   // acc at p=0

    int   cols[KDC];                       // permuted alongside cv by sort
    float cv[KDC];
#pragma unroll
    for (int k = 0; k < KDC; ++k) {
        cols[k] = row_cols[tid * KDC + k];
        cv[k]   = 0.f;
    }
    __syncthreads();

    // phase p: read S[p%3] (= T of iter p), atomics into S[(p+1)%3]
    // (pre-based), re-base S[(p+2)%3] (idle this phase).
#pragma unroll
    for (int p = 0; p < ITERS; ++p) {
        const int rd = p % 3, ac = (p + 1) % 3, zr = (p + 2) % 3;

        // ---- single-gather vc (issue all 6 ds_reads first) ----
        float v[KDC];
#pragma unroll
        for (int k = 0; k < KDC; ++k) v[k] = S[rd][cols[k]] - cv[k];

        // ---- marginalize iter p-1: out = T + (sp2-sp1)*soft ----
        if (p >= 1) {
            float2 o;
            o.x = fmaf(dsp, s0, S[rd][n0]);
            o.y = fmaf(dsp, s1, S[rd][n1]);
            *reinterpret_cast<float2*>(out + (size_t)p * TOT + b * NCOL + n0) = o;
        }
        if (p < ITERS - 1) {               // re-base next phase's acc buffer
            S[zr][n0] = base0;  S[zr][n1] = base1;
        }

        // ---- sort (v,cols) ascending by |v|: insertion network, 15 CE ----
#define CE(i, j) { bool sw = fabsf(v[i]) > fabsf(v[j]);                  \
        float tv = sw ? v[j] : v[i]; v[j] = sw ? v[i] : v[j]; v[i] = tv; \
        int tc = sw ? cols[j] : cols[i];                                  \
        cols[j] = sw ? cols[i] : cols[j]; cols[i] = tc; }
        CE(0,1)
        CE(1,2) CE(0,1)
        CE(2,3) CE(1,2) CE(0,1)
        CE(3,4) CE(2,3) CE(1,2) CE(0,1)
        CE(4,5) CE(3,4) CE(2,3) CE(1,2) CE(0,1)
#undef CE

        float        mg[KDC];
        unsigned int sb[KDC];
#pragma unroll
        for (int r = 0; r < KDC; ++r) {
            mg[r] = fabsf(v[r]);
            sb[r] = __float_as_uint(v[r]) & 0x80000000u;
        }
        const unsigned int Pb = sb[0] ^ sb[1] ^ sb[2] ^ sb[3] ^ sb[4] ^ sb[5];

        // leave-one-out dot via prefix/suffix over the sorted 6 (>= 0)
        float pre[KDC];
        pre[0] = 0.f;
#pragma unroll
        for (int r = 0; r < KDC - 1; ++r) pre[r + 1] = pre[r] + mg[r] * w[r];
        float suf[KDC];
        suf[KDC - 1] = 0.f;
#pragma unroll
        for (int r = KDC - 2; r >= 0; --r) suf[r] = suf[r + 1] + mg[r + 1] * w[r];

#pragma unroll
        for (int r = 0; r < KDC; ++r) {
            // cv = (P * sg_r) * loo; sign = xor of all sign bits except r's
            const float cvn = __uint_as_float(
                __float_as_uint(pre[r] + suf[r]) | (Pb ^ sb[r]));
            cv[r] = cvn;                       // stays aligned with cols[r]
            atomicAdd(&S[ac][cols[r]], cvn);   // block-local ds_add_f32
        }
        __syncthreads();
    }

    // final marginalize: iter ITERS-1's T is in S[ITERS%3]
    float2 o;
    o.x = fmaf(dsp, s0, S[ITERS % 3][n0]);
    o.y = fmaf(dsp, s1, S[ITERS % 3][n1]);
    *reinterpret_cast<float2*>(out + (size_t)ITERS * TOT + b * NCOL + n0) = o;
}

extern "C" void kernel_launch(void* const* d_in, const int* in_sizes, int n_in,
                              void* d_out, int out_size, void* d_ws, size_t ws_size,
                              hipStream_t stream) {
    const float* soft     = (const float*)d_in[0];
    // d_in[1] labels (int64) unused; d_in[2] dense H unused
    const int*   row_cols = (const int*)d_in[3];
    const float* W1       = (const float*)d_in[4];
    const float* W2       = (const float*)d_in[5];
    const float* bw1      = (const float*)d_in[6];
    const float* bw2      = (const float*)d_in[7];
    float* out = (float*)d_out;

    k_decode<<<dim3(BB), dim3(THR), 0, stream>>>(soft, row_cols, W1, W2,
                                                 bw1, bw2, out);
}